// Round 4
// baseline (443.826 us; speedup 1.0000x reference)
//
#include <hip/hip_runtime.h>
#include <cstdint>
#include <cstddef>

#define L_LAYERS 3
#define H_HEADS 8
#define D_EMB 128
#define DKV 16
#define FF_DIM 512
#define B_BATCH 32
#define N_SEQ 512
#define F_INP 16
#define OUT_DIM 3
#define M_ROWS (B_BATCH * N_SEQ)   // 16384

typedef unsigned short ushort_t;
typedef unsigned int uint_t;
typedef __attribute__((ext_vector_type(8))) short short8;
typedef __attribute__((ext_vector_type(4))) float f32x4;

__device__ inline ushort_t f2bf(float x) {   // RNE float->bf16
    union { float f; uint_t u; } v; v.f = x;
    uint_t r = v.u + 0x7fffu + ((v.u >> 16) & 1u);
    return (ushort_t)(r >> 16);
}

__device__ inline void gload16(const void* g, void* l) {
    __builtin_amdgcn_global_load_lds(
        (const __attribute__((address_space(1))) unsigned int*)g,
        (__attribute__((address_space(3))) unsigned int*)l, 16, 0, 0);
}

// ---------------- mask bit-pack ----------------
__global__ __launch_bounds__(256) void pack_mask_kernel(const int* __restrict__ mask,
                                                        unsigned long long* __restrict__ pm) {
    int gid = blockIdx.x * 256 + threadIdx.x;
    int v = mask[gid];
    unsigned long long bal = __ballot(v != 0);
    if ((threadIdx.x & 63) == 0) pm[gid >> 6] = bal;
}

// -------- Wq/Wk/Wv [L,H,D,DK] -> bf16 B^T layout [L][n=proj*128+h*16+k][d] --------
__global__ __launch_bounds__(256) void repack_qkv_bt_kernel(const float* __restrict__ Wq,
                                                            const float* __restrict__ Wk,
                                                            const float* __restrict__ Wv,
                                                            ushort_t* __restrict__ dst) {
    int idx = blockIdx.x * 256 + threadIdx.x;   // exactly L*384*128
    int d = idx & 127;
    int n = (idx >> 7) % 384;
    int l = idx / (384 * 128);
    int proj = n >> 7, hh = (n & 127) >> 4, kk = n & 15;
    const float* src = proj == 0 ? Wq : proj == 1 ? Wk : Wv;
    dst[idx] = f2bf(src[((size_t)(l * 8 + hh) * 128 + d) * 16 + kk]);
}

// -------- generic batched transpose to bf16: dst[b][c][r] = src[b][r][c] --------
__global__ __launch_bounds__(256) void tr_bf16_kernel(const float* __restrict__ src,
                                                      ushort_t* __restrict__ dst,
                                                      int R, int C, int total) {
    int idx = blockIdx.x * 256 + threadIdx.x;
    if (idx >= total) return;
    int b = idx / (R * C);
    int rem = idx - b * (R * C);
    int r = rem / C, c = rem - r * C;
    dst[(size_t)b * R * C + (size_t)c * R + r] = f2bf(src[idx]);
}

// ---------------- embed: h = relu(x @ We), write fp32 + bf16 ----------------
__global__ __launch_bounds__(256) void embed_kernel(const float* __restrict__ x,
                                                    const float* __restrict__ We,
                                                    float* __restrict__ hf,
                                                    ushort_t* __restrict__ hb) {
    const int t = threadIdx.x;
    const int d = t & 127;
    const int m = blockIdx.x * 2 + (t >> 7);
    const float* xr = x + (size_t)m * 16;
    float acc = 0.f;
#pragma unroll
    for (int k = 0; k < 16; k++) acc += xr[k] * We[k * 128 + d];
    acc = fmaxf(acc, 0.f);
    hf[(size_t)m * 128 + d] = acc;
    hb[(size_t)m * 128 + d] = f2bf(acc);
}

// ---------------- bf16 MFMA GEMM: C = [relu]([qsc]*(A @ Bt^T) [+bias] [+Cin]) ----------------
// Tiles: 128x128 (waves 2x2 of 64x64), 64x64 (waves 2x2 of 32x32).
// QS: multiply by 0.25 when blockIdx.x==0 (pre-scales Q part of QKV output).
template <int BM, int BN, bool QS, bool RELU, bool BIAS, bool RES, bool WF32, bool WB16>
__global__ __launch_bounds__(256) void gemm_bt(const ushort_t* __restrict__ A,
                                               const ushort_t* __restrict__ Bt,
                                               const float* __restrict__ bias,
                                               const float* __restrict__ Cin,
                                               float* __restrict__ Cf,
                                               ushort_t* __restrict__ Cb,
                                               int M, int N, int K) {
    constexpr int NI = (BM == 128) ? 4 : ((BN == 128) ? 4 : 2);
    constexpr int NJ = (BN == 128) ? ((BM == 128) ? 4 : 2) : 2;
    __shared__ __align__(16) ushort_t Asm[BM * 32];
    __shared__ __align__(16) ushort_t Bsm[BN * 32];
    const int tid = threadIdx.x;
    const int w = tid >> 6, l = tid & 63;
    const int m0 = blockIdx.y * BM, n0 = blockIdx.x * BN;
    const int WM = (BM == 128) ? (w & 1) * 64 : ((BN == 64) ? (w & 1) * 32 : 0);
    const int WN = (BM == 128) ? (w >> 1) * 64 : ((BN == 64) ? (w >> 1) * 32 : w * 32);
    const int lr = l & 15, lq = l >> 4;
    const int sar = w * 16 + (l >> 2);
    const int sac = (l & 3) * 8;

    f32x4 acc[NI][NJ];
#pragma unroll
    for (int i = 0; i < NI; i++)
#pragma unroll
        for (int j = 0; j < NJ; j++) acc[i][j] = (f32x4){0.f, 0.f, 0.f, 0.f};

    for (int k0 = 0; k0 < K; k0 += 32) {
#pragma unroll
        for (int it = 0; it < BM / 64; it++)
            gload16(A + (size_t)(m0 + it * 64 + sar) * K + k0 + sac,
                    &Asm[(it * 64 + sar) * 32 + sac]);
#pragma unroll
        for (int it = 0; it < BN / 64; it++)
            gload16(Bt + (size_t)(n0 + it * 64 + sar) * K + k0 + sac,
                    &Bsm[(it * 64 + sar) * 32 + sac]);
        __syncthreads();
        short8 af[NI], bfr[NJ];
#pragma unroll
        for (int i = 0; i < NI; i++)
            af[i] = *(const short8*)&Asm[(WM + i * 16 + lr) * 32 + lq * 8];
#pragma unroll
        for (int j = 0; j < NJ; j++)
            bfr[j] = *(const short8*)&Bsm[(WN + j * 16 + lr) * 32 + lq * 8];
#pragma unroll
        for (int i = 0; i < NI; i++)
#pragma unroll
            for (int j = 0; j < NJ; j++)
                acc[i][j] = __builtin_amdgcn_mfma_f32_16x16x32_bf16(af[i], bfr[j], acc[i][j], 0, 0, 0);
        __syncthreads();
    }

    const float qsc = (QS && blockIdx.x == 0) ? 0.25f : 1.0f;
    float bv[NJ];
#pragma unroll
    for (int j = 0; j < NJ; j++) {
        const int n = n0 + WN + j * 16 + lr;
        bv[j] = BIAS ? bias[n] : 0.f;
    }
#pragma unroll
    for (int i = 0; i < NI; i++) {
#pragma unroll
        for (int r = 0; r < 4; r++) {
            const int m = m0 + WM + i * 16 + lq * 4 + r;
#pragma unroll
            for (int j = 0; j < NJ; j++) {
                const int n = n0 + WN + j * 16 + lr;
                float v = acc[i][j][r] * qsc + bv[j];
                if (RES) v += Cin[(size_t)m * N + n];
                if (RELU) v = fmaxf(v, 0.f);
                if (WF32) Cf[(size_t)m * N + n] = v;
                if (WB16) Cb[(size_t)m * N + n] = f2bf(v);
            }
        }
    }
}

// ---------------- MFMA flash attention, occupancy-optimized ----------------
// qkv bf16 [16384][384]: q(prescaled x0.25)=h*16+k, k=128+h*16+k, v=256+h*16+k.
// Block = (b,h): 256 blocks, 512 threads = 8 waves, wave owns 4 q-tiles of 16.
// Chunked flash over 2x256 keys keeps score regs at acc[16] (VGPR<=128 -> 4 waves/SIMD).
// Raw-score max (mask-independent; valid since softmax is shift-invariant and |s| small),
// mask applied as multiply-zero after exp.
__global__ __launch_bounds__(512, 4) void attn_mfma_kernel(const ushort_t* __restrict__ qkv,
                                                           const uint_t* __restrict__ pm,
                                                           ushort_t* __restrict__ Aout) {
    __shared__ __align__(16) ushort_t KsA[512 * 8];   // k 0..7 per key
    __shared__ __align__(16) ushort_t KsB[512 * 8];   // k 8..15 per key
    __shared__ __align__(16) ushort_t Zrow[8];        // zeros (k 16..31)
    __shared__ __align__(16) ushort_t Vt[16 * 520];   // V^T [dv][key]
    __shared__ __align__(16) uint_t   Msk[8][256];    // per-wave mask words for current q-tile
    __shared__ __align__(16) ushort_t Ps[8][16 * 136];// per-wave P subchunk [16 q][128 key]

    const int tid = threadIdx.x;
    const int w = tid >> 6, l = tid & 63;
    const int lr = l & 15, lq = l >> 4;
    const int b = blockIdx.x >> 3;
    const int h = blockIdx.x & 7;
    const size_t base = (size_t)b * 512 * 384;

    if (tid < 4) ((uint_t*)Zrow)[tid] = 0u;
    {
        const ushort_t* g = qkv + base + (size_t)tid * 384 + 128 + h * 16;
        gload16(g, &KsA[tid * 8]);
        gload16(g + 8, &KsB[tid * 8]);
        const ushort_t* gv = qkv + base + (size_t)tid * 384 + 256 + h * 16;
        ushort_t tmp[16];
        *(uint4*)tmp = *(const uint4*)gv;
        *(uint4*)(tmp + 8) = *(const uint4*)(gv + 8);
#pragma unroll
        for (int d = 0; d < 16; d++) Vt[d * 520 + tid] = tmp[d];
    }
    __syncthreads();

    const ushort_t* kbase = (lq == 0) ? KsA : (lq == 1) ? KsB : Zrow;
    const ushort_t* kptr0 = (lq < 2) ? (kbase + lr * 8) : kbase;
    const int kstep = (lq < 2) ? 128 : 0;              // ushorts per 16-key tile
    const uint_t blo = 1u << lr, bhi = blo << 16;

    for (int qt = 0; qt < 4; qt++) {
        const int qr0 = w * 64 + qt * 16;
        gload16(pm + ((size_t)(b * 512 + qr0) * 16) + l * 4, &Msk[w][l * 4]);
        short8 af = *(const short8*)(qkv + base + (size_t)(qr0 + lr) * 384 + h * 16 + lq * 8);

        float mrun[4] = {-1e30f, -1e30f, -1e30f, -1e30f};
        float lsum[4] = {0.f, 0.f, 0.f, 0.f};          // lane-partial, reduced at end
        f32x4 oacc = (f32x4){0.f, 0.f, 0.f, 0.f};

#pragma unroll
        for (int c2 = 0; c2 < 2; c2++) {
            const ushort_t* kp = kptr0 + c2 * 16 * kstep;
            f32x4 acc[16];
#pragma unroll
            for (int j = 0; j < 16; j++) acc[j] = (f32x4){0.f, 0.f, 0.f, 0.f};
#pragma unroll
            for (int j = 0; j < 16; j++) {
                short8 bfr = *(const short8*)(kp + j * kstep);
                acc[j] = __builtin_amdgcn_mfma_f32_16x16x32_bf16(af, bfr, acc[j], 0, 0, 0);
            }
            __asm__ volatile("s_waitcnt vmcnt(0)" ::: "memory");   // Msk staged

#pragma unroll
            for (int r = 0; r < 4; r++) {
                float mx = acc[0][r];
#pragma unroll
                for (int j = 1; j < 16; j++) mx = fmaxf(mx, acc[j][r]);
#pragma unroll
                for (int o = 1; o < 16; o <<= 1) mx = fmaxf(mx, __shfl_xor(mx, o, 16));
                const float mnew = fmaxf(mrun[r], mx);
                const float alpha = __expf(mrun[r] - mnew);
                mrun[r] = mnew;
                lsum[r] *= alpha;
                oacc[r] *= alpha;
                const uint4 mw0 = *(const uint4*)&Msk[w][(lq * 4 + r) * 16 + c2 * 8];
                const uint4 mw1 = *(const uint4*)&Msk[w][(lq * 4 + r) * 16 + c2 * 8 + 4];
                float s0 = 0.f;
#pragma unroll
                for (int j = 0; j < 16; j++) {
                    const uint_t word = (j < 2) ? mw0.x : (j < 4) ? mw0.y : (j < 6) ? mw0.z
                                      : (j < 8) ? mw0.w : (j < 10) ? mw1.x : (j < 12) ? mw1.y
                                      : (j < 14) ? mw1.z : mw1.w;
                    const float p0 = __expf(acc[j][r] - mnew);
                    const float p = (word & ((j & 1) ? bhi : blo)) ? p0 : 0.f;
                    acc[j][r] = p;
                    s0 += p;
                }
                lsum[r] += s0;
            }

            // PV: 2 subchunks of 128 keys
#pragma unroll
            for (int sc = 0; sc < 2; sc++) {
#pragma unroll
                for (int jj = 0; jj < 8; jj++) {
#pragma unroll
                    for (int r = 0; r < 4; r++) {
                        union { float f; uint_t u; } pu;
                        pu.f = acc[sc * 8 + jj][r];
                        Ps[w][(lq * 4 + r) * 136 + jj * 16 + lr] = (ushort_t)((pu.u + 0x8000u) >> 16);
                    }
                }
#pragma unroll
                for (int kt = 0; kt < 4; kt++) {
                    short8 pa = *(const short8*)&Ps[w][lr * 136 + kt * 32 + lq * 8];
                    short8 vb = *(const short8*)&Vt[lr * 520 + c2 * 256 + sc * 128 + kt * 32 + lq * 8];
                    oacc = __builtin_amdgcn_mfma_f32_16x16x32_bf16(pa, vb, oacc, 0, 0, 0);
                }
            }
        }

#pragma unroll
        for (int r = 0; r < 4; r++) {
            float s = lsum[r];
#pragma unroll
            for (int o = 1; o < 16; o <<= 1) s += __shfl_xor(s, o, 16);
            const float ov = oacc[r] / s;
            Aout[(size_t)(b * 512 + qr0 + lq * 4 + r) * 128 + h * 16 + lr] = f2bf(ov);
        }
    }
}

// ------------- pooled readout part -------------
__global__ __launch_bounds__(128) void pool_kernel(const float* __restrict__ h,
                                                   const float* __restrict__ Wp,
                                                   const float* __restrict__ Wr,
                                                   const float* __restrict__ br,
                                                   float* __restrict__ pb) {
    const int b = blockIdx.x, t = threadIdx.x;
    __shared__ float pooled[128];
    __shared__ float rp[128];
    float acc = 0.f;
    const float* hb = h + (size_t)b * N_SEQ * D_EMB;
    for (int n = 0; n < N_SEQ; n++) acc += hb[n * D_EMB + t];
    pooled[t] = acc * (1.0f / N_SEQ);
    __syncthreads();
    float acc2 = 0.f;
    for (int d = 0; d < D_EMB; d++) acc2 += pooled[d] * Wp[d * D_EMB + t];
    rp[t] = fmaxf(acc2, 0.f);
    __syncthreads();
    if (t < OUT_DIM) {
        float a = br[t];
        for (int j = 0; j < D_EMB; j++) a += rp[j] * Wr[j * OUT_DIM + t];
        pb[b * OUT_DIM + t] = a;
    }
}

// ------------- final readout -------------
__global__ __launch_bounds__(128) void out_kernel(const float* __restrict__ h,
                                                  const float* __restrict__ Wr,
                                                  const float* __restrict__ pb,
                                                  float* __restrict__ out) {
    const int row = blockIdx.x, tid = threadIdx.x;
    __shared__ float rp[128];
    rp[tid] = fmaxf(h[(size_t)row * D_EMB + tid], 0.f);
    __syncthreads();
    if (tid < 96) {
        const int o = tid >> 5, j0 = tid & 31;
        float acc = 0.f;
        for (int j = j0; j < 128; j += 32) acc += rp[j] * Wr[(128 + j) * OUT_DIM + o];
        for (int off = 16; off; off >>= 1) acc += __shfl_down(acc, off, 32);
        if (j0 == 0) out[(size_t)row * OUT_DIM + o] = acc + pb[(row >> 9) * OUT_DIM + o];
    }
}

extern "C" void kernel_launch(void* const* d_in, const int* in_sizes, int n_in,
                              void* d_out, int out_size, void* d_ws, size_t ws_size,
                              hipStream_t stream) {
    const float* x    = (const float*)d_in[0];
    const int*   mask = (const int*)d_in[1];
    const float* We   = (const float*)d_in[2];
    const float* Wq   = (const float*)d_in[3];
    const float* Wk   = (const float*)d_in[4];
    const float* Wv   = (const float*)d_in[5];
    const float* Wout = (const float*)d_in[6];
    const float* Wff1 = (const float*)d_in[7];
    const float* bff1 = (const float*)d_in[8];
    const float* Wff2 = (const float*)d_in[9];
    const float* bff2 = (const float*)d_in[10];
    const float* Wp   = (const float*)d_in[11];
    const float* Wr   = (const float*)d_in[12];
    const float* br   = (const float*)d_in[13];
    float* out = (float*)d_out;

    char* ws = (char*)d_ws;
    unsigned long long* pm64 = (unsigned long long*)(ws + 0);        // 1 MiB
    const uint_t* pm32       = (const uint_t*)(ws + 0);
    ushort_t* wqkvT = (ushort_t*)(ws + 1048576);                     // 288 KiB
    ushort_t* woutT = (ushort_t*)(ws + 1343488);                     // 96 KiB
    ushort_t* wff1T = (ushort_t*)(ws + 1441792);                     // 384 KiB
    ushort_t* wff2T = (ushort_t*)(ws + 1835008);                     // 384 KiB
    float*    pbbuf = (float*)(ws + 2228224);                        // 384 B
    float*    hbuf  = (float*)(ws + 4194304);                        // 8 MiB fp32 residual
    ushort_t* hb16  = (ushort_t*)(ws + 12582912);                    // 4 MiB bf16 mirror of h
    ushort_t* qkv16 = (ushort_t*)(ws + 16777216);                    // 12 MiB bf16 QKV
    ushort_t* t16   = (ushort_t*)(ws + 16777216);                    // 16 MiB bf16 FFN mid (aliases qkv16)
    ushort_t* a16   = (ushort_t*)(ws + 41943040);                    // 4 MiB bf16 attn out

    pack_mask_kernel<<<(B_BATCH * N_SEQ * N_SEQ) / 256, 256, 0, stream>>>(mask, pm64);
    repack_qkv_bt_kernel<<<576, 256, 0, stream>>>(Wq, Wk, Wv, wqkvT);
    tr_bf16_kernel<<<192, 256, 0, stream>>>(Wout, woutT, 128, 128, 3 * 128 * 128);
    tr_bf16_kernel<<<768, 256, 0, stream>>>(Wff1, wff1T, 128, 512, 3 * 128 * 512);
    tr_bf16_kernel<<<768, 256, 0, stream>>>(Wff2, wff2T, 512, 128, 3 * 512 * 128);

    embed_kernel<<<M_ROWS / 2, 256, 0, stream>>>(x, We, hbuf, hb16);

    for (int l = 0; l < L_LAYERS; l++) {
        // QKV (Q prescaled by 0.25 in epilogue of block x=0)
        gemm_bt<128, 128, true, false, false, false, false, true>
            <<<dim3(3, M_ROWS / 128), 256, 0, stream>>>(
            hb16, wqkvT + (size_t)l * 384 * 128, nullptr, nullptr, nullptr, qkv16,
            M_ROWS, 384, 128);
        // MFMA flash attention -> a16 bf16
        attn_mfma_kernel<<<256, 512, 0, stream>>>(qkv16, pm32, a16);
        // h += a16 @ Wout   (64x64 tiles -> 512 blocks)
        gemm_bt<64, 64, false, false, false, true, true, true>
            <<<dim3(2, M_ROWS / 64), 256, 0, stream>>>(
            a16, woutT + (size_t)l * 128 * 128, nullptr, hbuf, hbuf, hb16,
            M_ROWS, 128, 128);
        // t = relu(h @ Wff1 + bff1)
        gemm_bt<128, 128, false, true, true, false, false, true>
            <<<dim3(4, M_ROWS / 128), 256, 0, stream>>>(
            hb16, wff1T + (size_t)l * 512 * 128, bff1 + l * 512, nullptr, nullptr, t16,
            M_ROWS, 512, 128);
        // h += t16 @ Wff2 + bff2   (64x64 tiles -> 512 blocks)
        gemm_bt<64, 64, false, false, true, true, true, true>
            <<<dim3(2, M_ROWS / 64), 256, 0, stream>>>(
            t16, wff2T + (size_t)l * 128 * 512, bff2 + l * 128, hbuf, hbuf, hb16,
            M_ROWS, 128, 512);
    }

    pool_kernel<<<B_BATCH, 128, 0, stream>>>(hbuf, Wp, Wr, br, pbbuf);
    out_kernel<<<M_ROWS, 128, 0, stream>>>(hbuf, Wr, pbbuf, out);
}